// Round 1
// baseline (1359.447 us; speedup 1.0000x reference)
//
#include <hip/hip_runtime.h>
#include <cstdint>
#include <cstddef>

typedef __bf16 bf16_t;
typedef __bf16 bf16x8 __attribute__((ext_vector_type(8)));
typedef float f32x4 __attribute__((ext_vector_type(4)));

// ---------------- conversions ----------------
__global__ void conv_k(const float* __restrict__ in, bf16_t* __restrict__ out, int n8) {
    int id = blockIdx.x * 256 + threadIdx.x;
    if (id >= n8) return;
    const float4* p = (const float4*)in;
    float4 a = p[2 * id], b = p[2 * id + 1];
    bf16x8 o;
    o[0] = (bf16_t)a.x; o[1] = (bf16_t)a.y; o[2] = (bf16_t)a.z; o[3] = (bf16_t)a.w;
    o[4] = (bf16_t)b.x; o[5] = (bf16_t)b.y; o[6] = (bf16_t)b.z; o[7] = (bf16_t)b.w;
    *(bf16x8*)(out + (size_t)id * 8) = o;
}

// ---------------- edge-index dtype detection ----------------
// If edge_index is int64, every odd 32-bit dword (high half of values < 2^31) is 0.
// If int32, odd dwords are random node ids in [0,N): P(all 256 are 0) ~ 1e-1280.
__global__ void detect_k(const int* __restrict__ ei, int* __restrict__ flag) {
    int v = ei[2 * threadIdx.x + 1];
    if (v != 0) atomicOr(flag, 1);   // 1 => int32 layout
}

__global__ void hist_k(const void* __restrict__ ei, const int* __restrict__ flag,
                       int E, int* __restrict__ counts) {
    int e = blockIdx.x * 256 + threadIdx.x;
    if (e >= E) return;
    int dst = (*flag) ? ((const int*)ei)[e] : (int)((const long long*)ei)[e];
    atomicAdd(&counts[dst], 1);
}

__global__ void scan_k(const int* __restrict__ counts, int* __restrict__ offs,
                       int* __restrict__ cursor, int N, int E) {
    __shared__ int lds[1024];
    int t = threadIdx.x;
    int chunk = (N + 1023) >> 10;
    int beg = t * chunk; if (beg > N) beg = N;
    int end = beg + chunk; if (end > N) end = N;
    int s = 0;
    for (int i = beg; i < end; i++) s += counts[i];
    lds[t] = s;
    __syncthreads();
    for (int off = 1; off < 1024; off <<= 1) {
        int add = (t >= off) ? lds[t - off] : 0;
        __syncthreads();
        lds[t] += add;
        __syncthreads();
    }
    int run = lds[t] - s;  // exclusive prefix of this thread's chunk
    for (int i = beg; i < end; i++) {
        offs[i] = run; cursor[i] = run;
        run += counts[i];
    }
    if (t == 0) offs[N] = E;
}

__global__ void fill_k(const void* __restrict__ ei, const int* __restrict__ flag,
                       int E, int* __restrict__ cursor, int* __restrict__ csr) {
    int e = blockIdx.x * 256 + threadIdx.x;
    if (e >= E) return;
    int dst, src;
    if (*flag) { dst = ((const int*)ei)[e]; src = ((const int*)ei)[E + e]; }
    else       { dst = (int)((const long long*)ei)[e]; src = (int)((const long long*)ei)[E + e]; }
    int pos = atomicAdd(&cursor[dst], 1);
    csr[pos] = src;
}

// one wave per node; lane owns 2 channels; each neighbor read is a coalesced 512B row
__global__ void gather_k(const float* __restrict__ x, const int* __restrict__ offs,
                         const int* __restrict__ csr, float* __restrict__ agg, int N) {
    int w = (blockIdx.x * 256 + threadIdx.x) >> 6;
    if (w >= N) return;
    int lane = threadIdx.x & 63;
    int s = offs[w], e = offs[w + 1];
    float a0 = 0.f, a1 = 0.f;
    for (int i = s; i < e; i++) {
        int src = csr[i];
        float2 v = *(const float2*)(x + (size_t)src * 128 + lane * 2);
        a0 += v.x; a1 += v.y;
    }
    *(float2*)(agg + (size_t)w * 128 + lane * 2) = make_float2(a0, a1);
}

// ---------------- GEMM0: h = x@lin_w^T + lin_b + (1+eps)*[x,x] + [agg,agg] -> bf16 ----------------
// mfma_f32_16x16x32_bf16 layouts (learn_hip m89-verified):
//   A: lane holds A[l&15][(l>>4)*8 + i], i=0..7 (contiguous k)
//   B: lane holds B[k][l&15], same k -> W row-major [out][in] loads contiguously
//   D: reg i <-> out[row=(l>>4)*4+i][col=l&15]
__global__ __launch_bounds__(256) void gemm0_k(
    const bf16_t* __restrict__ xbf, const bf16_t* __restrict__ wlin,
    const float* __restrict__ xf, const float* __restrict__ agg,
    const float* __restrict__ lin_b, const float* __restrict__ eps_p,
    bf16_t* __restrict__ hbf, int N)
{
    const int lane = threadIdx.x & 63, wid = threadIdx.x >> 6;
    const int rows0 = blockIdx.x * 64 + wid * 16;
    const int l15 = lane & 15, l4 = lane >> 4;
    int r_a = rows0 + l15; if (r_a > N - 1) r_a = N - 1;
    f32x4 acc[16];
#pragma unroll
    for (int i = 0; i < 16; i++) acc[i] = f32x4{0.f, 0.f, 0.f, 0.f};
    const int kb = l4 * 8;
#pragma unroll
    for (int ks = 0; ks < 4; ks++) {
        int k0 = ks * 32 + kb;
        bf16x8 a = *(const bf16x8*)(xbf + (size_t)r_a * 128 + k0);
#pragma unroll
        for (int ot = 0; ot < 16; ot++) {
            bf16x8 b = *(const bf16x8*)(wlin + (size_t)(ot * 16 + l15) * 128 + k0);
            acc[ot] = __builtin_amdgcn_mfma_f32_16x16x32_bf16(a, b, acc[ot], 0, 0, 0);
        }
    }
    const float onepe = 1.f + *eps_p;
    const int rb = rows0 + l4 * 4;
#pragma unroll
    for (int ot = 0; ot < 16; ot++) {
        int c = ot * 16 + l15;
        int cm = c & 127;
        float bb = lin_b[c];
#pragma unroll
        for (int i = 0; i < 4; i++) {
            int r = rb + i;
            if (r < N) {
                float v = acc[ot][i] + bb + onepe * xf[(size_t)r * 128 + cm] + agg[(size_t)r * 128 + cm];
                hbf[(size_t)r * 256 + c] = (bf16_t)v;
            }
        }
    }
}

// ---------------- generic K=256 GEMM with optional fused input-BN+ReLU, stats, final bias ----------------
template<int OT, bool BNIN, bool STATS, bool FINAL>
__global__ __launch_bounds__(256) void gemm_k(
    const bf16_t* __restrict__ A, const bf16_t* __restrict__ W,
    const float* __restrict__ scale, const float* __restrict__ shift,
    float* __restrict__ sums, float* __restrict__ sqs,
    const float* __restrict__ bias,
    bf16_t* __restrict__ Obf, float* __restrict__ Of, int N)
{
    __shared__ float ls[256], lh[256];
    if (BNIN) {
        int t = threadIdx.x;
        ls[t] = scale[t]; lh[t] = shift[t];
        __syncthreads();
    }
    const int lane = threadIdx.x & 63, wid = threadIdx.x >> 6;
    const int rows0 = blockIdx.x * 64 + wid * 16;
    const int l15 = lane & 15, l4 = lane >> 4;
    int r_a = rows0 + l15; if (r_a > N - 1) r_a = N - 1;
    f32x4 acc[OT];
#pragma unroll
    for (int i = 0; i < OT; i++) acc[i] = f32x4{0.f, 0.f, 0.f, 0.f};
    const int kb = l4 * 8;
#pragma unroll
    for (int ks = 0; ks < 8; ks++) {
        int k0 = ks * 32 + kb;
        bf16x8 a = *(const bf16x8*)(A + (size_t)r_a * 256 + k0);
        if (BNIN) {
            bf16x8 t;
#pragma unroll
            for (int i = 0; i < 8; i++) {
                float f = (float)a[i] * ls[k0 + i] + lh[k0 + i];
                f = f > 0.f ? f : 0.f;
                t[i] = (bf16_t)f;
            }
            a = t;
        }
#pragma unroll
        for (int ot = 0; ot < OT; ot++) {
            bf16x8 b = *(const bf16x8*)(W + (size_t)(ot * 16 + l15) * 256 + k0);
            acc[ot] = __builtin_amdgcn_mfma_f32_16x16x32_bf16(a, b, acc[ot], 0, 0, 0);
        }
    }
    const int rb = rows0 + l4 * 4;
#pragma unroll
    for (int ot = 0; ot < OT; ot++) {
        int c = ot * 16 + l15;
        float s = 0.f, q = 0.f;
#pragma unroll
        for (int i = 0; i < 4; i++) {
            int r = rb + i;
            if (FINAL) {
                if (r < N) Of[(size_t)r * (OT * 16) + c] = acc[ot][i] + bias[c];
            } else {
                bf16_t hv = (bf16_t)acc[ot][i];
                if (r < N) Obf[(size_t)r * 256 + c] = hv;
                if (STATS) {
                    float v = (r < N) ? (float)hv : 0.f;
                    s += v; q += v * v;
                }
            }
        }
        if (STATS) {
            s += __shfl_xor(s, 16); s += __shfl_xor(s, 32);
            q += __shfl_xor(q, 16); q += __shfl_xor(q, 32);
            if (lane < 16) {
                atomicAdd(&sums[c], s);
                atomicAdd(&sqs[c], q);
            }
        }
    }
}

__global__ void finalize_k(const float* __restrict__ sum, const float* __restrict__ sq,
                           const float* __restrict__ g, const float* __restrict__ b,
                           float* __restrict__ scale, float* __restrict__ shift, float invN) {
    int t = threadIdx.x;
    float mean = sum[t] * invN;
    float var = sq[t] * invN - mean * mean;
    float s = g[t] * rsqrtf(var + 1e-5f);
    scale[t] = s;
    shift[t] = b[t] - mean * s;
}

extern "C" void kernel_launch(void* const* d_in, const int* in_sizes, int n_in,
                              void* d_out, int out_size, void* d_ws, size_t ws_size,
                              hipStream_t stream)
{
    const int N = in_sizes[0] / 128;
    const int E = in_sizes[1] / 2;
    const float* x     = (const float*)d_in[0];
    const void*  ei    = d_in[1];
    const float* lin_w = (const float*)d_in[2];
    const float* lin_b = (const float*)d_in[3];
    const float* eps   = (const float*)d_in[4];
    const float* w1    = (const float*)d_in[5];
    const float* g1    = (const float*)d_in[6];
    const float* b1    = (const float*)d_in[7];
    const float* w2    = (const float*)d_in[8];
    const float* g2    = (const float*)d_in[9];
    const float* b2    = (const float*)d_in[10];
    const float* w3    = (const float*)d_in[11];
    const float* b3    = (const float*)d_in[12];
    float* out = (float*)d_out;

    char* ws = (char*)d_ws;
    size_t o = 0;
    auto alloc = [&](size_t bytes) -> char* {
        char* p = ws + o;
        o = (o + bytes + 255) & ~(size_t)255;
        return p;
    };
    float*  agg    = (float*)alloc((size_t)N * 128 * 4);
    bf16_t* xbf    = (bf16_t*)alloc((size_t)N * 128 * 2);
    bf16_t* hbf    = (bf16_t*)alloc((size_t)N * 256 * 2);  // h for GEMM1, reused as t2
    bf16_t* t1     = (bf16_t*)alloc((size_t)N * 256 * 2);
    bf16_t* wlinb  = (bf16_t*)alloc((size_t)256 * 128 * 2);
    bf16_t* w1b    = (bf16_t*)alloc((size_t)256 * 256 * 2);
    bf16_t* w2b    = (bf16_t*)alloc((size_t)256 * 256 * 2);
    bf16_t* w3b    = (bf16_t*)alloc((size_t)128 * 256 * 2);
    float*  stats  = (float*)alloc(4 * 256 * 4);  // sum1, sq1, sum2, sq2
    float*  scsh   = (float*)alloc(4 * 256 * 4);  // scale1, shift1, scale2, shift2
    int*    counts = (int*)alloc((size_t)(N + 1) * 4);
    int*    offs   = (int*)alloc((size_t)(N + 1) * 4);
    int*    cursor = (int*)alloc((size_t)N * 4);
    int*    csr    = (int*)alloc((size_t)E * 4);
    int*    flag   = (int*)alloc(4);

    hipMemsetAsync(counts, 0, (size_t)(N + 1) * 4, stream);
    hipMemsetAsync(stats, 0, 4 * 256 * 4, stream);
    hipMemsetAsync(flag, 0, 4, stream);

    // dtype conversions (fp32 -> bf16)
    int nx8 = N * 128 / 8;
    conv_k<<<(nx8 + 255) / 256, 256, 0, stream>>>(x, xbf, nx8);
    conv_k<<<16, 256, 0, stream>>>(lin_w, wlinb, 4096);
    conv_k<<<32, 256, 0, stream>>>(w1, w1b, 8192);
    conv_k<<<32, 256, 0, stream>>>(w2, w2b, 8192);
    conv_k<<<16, 256, 0, stream>>>(w3, w3b, 4096);

    // CSR build + gather (replaces 205M-fp32-atomic scatter)
    detect_k<<<1, 256, 0, stream>>>((const int*)ei, flag);
    hist_k<<<(E + 255) / 256, 256, 0, stream>>>(ei, flag, E, counts);
    scan_k<<<1, 1024, 0, stream>>>(counts, offs, cursor, N, E);
    fill_k<<<(E + 255) / 256, 256, 0, stream>>>(ei, flag, E, cursor, csr);
    gather_k<<<(N + 3) / 4, 256, 0, stream>>>(x, offs, csr, agg, N);

    const int gblocks = (N + 63) / 64;
    // h = x@lin_w^T + lin_b + (1+eps)*[x,x] + [agg,agg]
    gemm0_k<<<gblocks, 256, 0, stream>>>(xbf, wlinb, x, agg, lin_b, eps, hbf, N);
    // t1 = h@w1^T (+ BN1 stats)
    gemm_k<16, false, true, false><<<gblocks, 256, 0, stream>>>(
        hbf, w1b, nullptr, nullptr, stats + 0, stats + 256, nullptr, t1, nullptr, N);
    finalize_k<<<1, 256, 0, stream>>>(stats + 0, stats + 256, g1, b1, scsh + 0, scsh + 256, 1.f / (float)N);
    // t2 = relu(BN1(t1))@w2^T (+ BN2 stats)  [t2 overwrites hbf]
    gemm_k<16, true, true, false><<<gblocks, 256, 0, stream>>>(
        t1, w2b, scsh + 0, scsh + 256, stats + 512, stats + 768, nullptr, hbf, nullptr, N);
    finalize_k<<<1, 256, 0, stream>>>(stats + 512, stats + 768, g2, b2, scsh + 512, scsh + 768, 1.f / (float)N);
    // out = relu(BN2(t2))@w3^T + b3
    gemm_k<8, true, false, true><<<gblocks, 256, 0, stream>>>(
        hbf, w3b, scsh + 512, scsh + 768, nullptr, nullptr, b3, nullptr, out, N);
}

// Round 2
// 1016.957 us; speedup vs baseline: 1.3368x; 1.3368x over previous
//
#include <hip/hip_runtime.h>
#include <cstdint>
#include <cstddef>

typedef __bf16 bf16_t;
typedef __bf16 bf16x8 __attribute__((ext_vector_type(8)));
typedef __bf16 bf16x2 __attribute__((ext_vector_type(2)));
typedef float f32x4 __attribute__((ext_vector_type(4)));

__device__ __forceinline__ float bf2f(unsigned short u) {
    union { unsigned int i; float f; } c; c.i = ((unsigned int)u) << 16; return c.f;
}

// ---------------- conversions ----------------
// plain fp32 -> bf16 (weights)
__global__ void conv_k(const float* __restrict__ in, bf16_t* __restrict__ out, int n8) {
    int id = blockIdx.x * 256 + threadIdx.x;
    if (id >= n8) return;
    const float4* p = (const float4*)in;
    float4 a = p[2 * id], b = p[2 * id + 1];
    bf16x8 o;
    o[0] = (bf16_t)a.x; o[1] = (bf16_t)a.y; o[2] = (bf16_t)a.z; o[3] = (bf16_t)a.w;
    o[4] = (bf16_t)b.x; o[5] = (bf16_t)b.y; o[6] = (bf16_t)b.z; o[7] = (bf16_t)b.w;
    *(bf16x8*)(out + (size_t)id * 8) = o;
}

// x fp32 -> cols 0..127 of interleaved ha[N][256]
__global__ void conv_x_k(const float* __restrict__ in, bf16_t* __restrict__ ha, int n8) {
    int id = blockIdx.x * 256 + threadIdx.x;
    if (id >= n8) return;
    const float4* p = (const float4*)in;
    float4 a = p[2 * id], b = p[2 * id + 1];
    bf16x8 o;
    o[0] = (bf16_t)a.x; o[1] = (bf16_t)a.y; o[2] = (bf16_t)a.z; o[3] = (bf16_t)a.w;
    o[4] = (bf16_t)b.x; o[5] = (bf16_t)b.y; o[6] = (bf16_t)b.z; o[7] = (bf16_t)b.w;
    int row = id >> 4, ch = id & 15;
    *(bf16x8*)(ha + (size_t)row * 256 + ch * 8) = o;
}

// W2[c][k] = (k<128 ? lin_w[c][k] : 0) + ((k&127)==(c&127) ? (k<128 ? 1+eps : 1) : 0)
__global__ void wprep0_k(const float* __restrict__ lin_w, const float* __restrict__ eps_p,
                         bf16_t* __restrict__ w0b) {
    int c = blockIdx.x, k = threadIdx.x;
    float v = (k < 128) ? lin_w[c * 128 + k] : 0.f;
    if ((k & 127) == (c & 127)) v += (k < 128) ? (1.f + *eps_p) : 1.f;
    w0b[c * 256 + k] = (bf16_t)v;
}

// ---------------- edge-index dtype detection ----------------
__global__ void detect_k(const int* __restrict__ ei, int* __restrict__ flag) {
    int v = ei[2 * threadIdx.x + 1];
    if (v != 0) atomicOr(flag, 1);   // 1 => int32 layout
}

__global__ void hist_k(const void* __restrict__ ei, const int* __restrict__ flag,
                       int E, int* __restrict__ counts) {
    int e = blockIdx.x * 256 + threadIdx.x;
    if (e >= E) return;
    int dst = (*flag) ? ((const int*)ei)[e] : (int)((const long long*)ei)[e];
    atomicAdd(&counts[dst], 1);
}

__global__ void scan_k(const int* __restrict__ counts, int* __restrict__ offs,
                       int* __restrict__ cursor, int N, int E) {
    __shared__ int lds[1024];
    int t = threadIdx.x;
    int chunk = (N + 1023) >> 10;
    int beg = t * chunk; if (beg > N) beg = N;
    int end = beg + chunk; if (end > N) end = N;
    int s = 0;
    for (int i = beg; i < end; i++) s += counts[i];
    lds[t] = s;
    __syncthreads();
    for (int off = 1; off < 1024; off <<= 1) {
        int add = (t >= off) ? lds[t - off] : 0;
        __syncthreads();
        lds[t] += add;
        __syncthreads();
    }
    int run = lds[t] - s;
    for (int i = beg; i < end; i++) {
        offs[i] = run; cursor[i] = run;
        run += counts[i];
    }
    if (t == 0) offs[N] = E;
}

__global__ void fill_k(const void* __restrict__ ei, const int* __restrict__ flag,
                       int E, int* __restrict__ cursor, int* __restrict__ csr) {
    int e = blockIdx.x * 256 + threadIdx.x;
    if (e >= E) return;
    int dst, src;
    if (*flag) { dst = ((const int*)ei)[e]; src = ((const int*)ei)[E + e]; }
    else       { dst = (int)((const long long*)ei)[e]; src = (int)((const long long*)ei)[E + e]; }
    int pos = atomicAdd(&cursor[dst], 1);
    csr[pos] = src;
}

// one wave per node; reads bf16 x rows (cols 0..127 of ha), writes bf16 agg (cols 128..255)
__global__ void gather_k(bf16_t* __restrict__ ha, const int* __restrict__ offs,
                         const int* __restrict__ csr, int N) {
    int w = (blockIdx.x * 256 + threadIdx.x) >> 6;
    if (w >= N) return;
    int lane = threadIdx.x & 63;
    int s = offs[w], e = offs[w + 1];
    float a0 = 0.f, a1 = 0.f;
    for (int i = s; i < e; i++) {
        int src = csr[i];
        unsigned int v = *(const unsigned int*)(ha + (size_t)src * 256 + lane * 2);
        a0 += bf2f((unsigned short)(v & 0xffff));
        a1 += bf2f((unsigned short)(v >> 16));
    }
    bf16x2 o; o[0] = (bf16_t)a0; o[1] = (bf16_t)a1;
    *(bf16x2*)(ha + (size_t)w * 256 + 128 + lane * 2) = o;
}

// ---------------- K=256 MFMA GEMM, 128 rows/block, 32 rows/wave ----------------
// mfma_f32_16x16x32_bf16 (m89-verified): A lane holds A[l&15][(l>>4)*8+i];
// B lane holds B[k][l&15] (W row-major [out][in] loads contiguously); D reg i
// <-> out[row=(l>>4)*4+i][col=l&15].
template<int OT, bool BNIN, bool STATS, bool FINAL, bool BIAS>
__global__ __launch_bounds__(256) void gemm_k(
    const bf16_t* __restrict__ A, const bf16_t* __restrict__ W,
    const float* __restrict__ scale, const float* __restrict__ shift,
    float* __restrict__ sums, float* __restrict__ sqs,
    const float* __restrict__ bias,
    bf16_t* __restrict__ Obf, float* __restrict__ Of, int N)
{
    __shared__ float ls[BNIN ? 256 : 1], lh[BNIN ? 256 : 1];
    __shared__ float ps[STATS ? 4 : 1][STATS ? 256 : 1];
    __shared__ float pq[STATS ? 4 : 1][STATS ? 256 : 1];
    if constexpr (BNIN) {
        int t = threadIdx.x;
        ls[t] = scale[t]; lh[t] = shift[t];
        __syncthreads();
    }
    const int lane = threadIdx.x & 63, wid = threadIdx.x >> 6;
    const int l15 = lane & 15, l4 = lane >> 4;
    const int rows0 = blockIdx.x * 128 + wid * 32;
    int ra0 = rows0 + l15;      if (ra0 > N - 1) ra0 = N - 1;
    int ra1 = rows0 + 16 + l15; if (ra1 > N - 1) ra1 = N - 1;
    f32x4 acc0[OT], acc1[OT];
#pragma unroll
    for (int i = 0; i < OT; i++) { acc0[i] = f32x4{0.f,0.f,0.f,0.f}; acc1[i] = f32x4{0.f,0.f,0.f,0.f}; }
    const int kb = l4 * 8;
#pragma unroll
    for (int ks = 0; ks < 8; ks++) {
        int k0 = ks * 32 + kb;
        bf16x8 a0 = *(const bf16x8*)(A + (size_t)ra0 * 256 + k0);
        bf16x8 a1 = *(const bf16x8*)(A + (size_t)ra1 * 256 + k0);
        if constexpr (BNIN) {
            bf16x8 t0, t1;
#pragma unroll
            for (int i = 0; i < 8; i++) {
                float sc = ls[k0 + i], sh = lh[k0 + i];
                float f0 = (float)a0[i] * sc + sh; f0 = f0 > 0.f ? f0 : 0.f; t0[i] = (bf16_t)f0;
                float f1 = (float)a1[i] * sc + sh; f1 = f1 > 0.f ? f1 : 0.f; t1[i] = (bf16_t)f1;
            }
            a0 = t0; a1 = t1;
        }
#pragma unroll
        for (int ot = 0; ot < OT; ot++) {
            bf16x8 b = *(const bf16x8*)(W + (size_t)(ot * 16 + l15) * 256 + k0);
            acc0[ot] = __builtin_amdgcn_mfma_f32_16x16x32_bf16(a0, b, acc0[ot], 0, 0, 0);
            acc1[ot] = __builtin_amdgcn_mfma_f32_16x16x32_bf16(a1, b, acc1[ot], 0, 0, 0);
        }
    }
    const int rb0 = rows0 + l4 * 4, rb1 = rows0 + 16 + l4 * 4;
#pragma unroll
    for (int ot = 0; ot < OT; ot++) {
        int c = ot * 16 + l15;
        float s = 0.f, q = 0.f;
#pragma unroll
        for (int half = 0; half < 2; half++) {
            int rb = half ? rb1 : rb0;
            f32x4 av = half ? acc1[ot] : acc0[ot];
#pragma unroll
            for (int i = 0; i < 4; i++) {
                int r = rb + i;
                if constexpr (FINAL) {
                    if (r < N) Of[(size_t)r * (OT * 16) + c] = av[i] + bias[c];
                } else {
                    float v = av[i];
                    if constexpr (BIAS) v += bias[c];
                    bf16_t hv = (bf16_t)v;
                    if (r < N) Obf[(size_t)r * 256 + c] = hv;
                    if constexpr (STATS) {
                        float vv = (r < N) ? (float)hv : 0.f;
                        s += vv; q += vv * vv;
                    }
                }
            }
        }
        if constexpr (STATS) {
            s += __shfl_xor(s, 16); s += __shfl_xor(s, 32);
            q += __shfl_xor(q, 16); q += __shfl_xor(q, 32);
            if (lane < 16) { ps[wid][c] = s; pq[wid][c] = q; }
        }
    }
    if constexpr (STATS) {
        __syncthreads();
        int t = threadIdx.x;
        float S = ps[0][t] + ps[1][t] + ps[2][t] + ps[3][t];
        float Q = pq[0][t] + pq[1][t] + pq[2][t] + pq[3][t];
        atomicAdd(&sums[t], S);
        atomicAdd(&sqs[t], Q);
    }
}

__global__ void finalize_k(const float* __restrict__ sum, const float* __restrict__ sq,
                           const float* __restrict__ g, const float* __restrict__ b,
                           float* __restrict__ scale, float* __restrict__ shift, float invN) {
    int t = threadIdx.x;
    float mean = sum[t] * invN;
    float var = sq[t] * invN - mean * mean;
    float s = g[t] * rsqrtf(var + 1e-5f);
    scale[t] = s;
    shift[t] = b[t] - mean * s;
}

extern "C" void kernel_launch(void* const* d_in, const int* in_sizes, int n_in,
                              void* d_out, int out_size, void* d_ws, size_t ws_size,
                              hipStream_t stream)
{
    const int N = in_sizes[0] / 128;
    const int E = in_sizes[1] / 2;
    const float* x     = (const float*)d_in[0];
    const void*  ei    = d_in[1];
    const float* lin_w = (const float*)d_in[2];
    const float* lin_b = (const float*)d_in[3];
    const float* eps   = (const float*)d_in[4];
    const float* w1    = (const float*)d_in[5];
    const float* g1    = (const float*)d_in[6];
    const float* b1    = (const float*)d_in[7];
    const float* w2    = (const float*)d_in[8];
    const float* g2    = (const float*)d_in[9];
    const float* b2    = (const float*)d_in[10];
    const float* w3    = (const float*)d_in[11];
    const float* b3    = (const float*)d_in[12];
    float* out = (float*)d_out;

    char* ws = (char*)d_ws;
    size_t o = 0;
    auto alloc = [&](size_t bytes) -> char* {
        char* p = ws + o;
        o = (o + bytes + 255) & ~(size_t)255;
        return p;
    };
    bf16_t* ha     = (bf16_t*)alloc((size_t)N * 256 * 2);  // [x | agg], later t1
    bf16_t* hb     = (bf16_t*)alloc((size_t)N * 256 * 2);  // h, later t2
    bf16_t* w0b    = (bf16_t*)alloc((size_t)256 * 256 * 2);
    bf16_t* w1b    = (bf16_t*)alloc((size_t)256 * 256 * 2);
    bf16_t* w2b    = (bf16_t*)alloc((size_t)256 * 256 * 2);
    bf16_t* w3b    = (bf16_t*)alloc((size_t)128 * 256 * 2);
    float*  stats  = (float*)alloc(4 * 256 * 4);  // sum1, sq1, sum2, sq2
    float*  scsh   = (float*)alloc(4 * 256 * 4);  // scale1, shift1, scale2, shift2
    int*    counts = (int*)alloc((size_t)(N + 1) * 4);
    int*    offs   = (int*)alloc((size_t)(N + 1) * 4);
    int*    cursor = (int*)alloc((size_t)N * 4);
    int*    csr    = (int*)alloc((size_t)E * 4);
    int*    flag   = (int*)alloc(4);

    hipMemsetAsync(counts, 0, (size_t)(N + 1) * 4, stream);
    hipMemsetAsync(stats, 0, 4 * 256 * 4, stream);
    hipMemsetAsync(flag, 0, 4, stream);

    // conversions / weight prep
    int nx8 = N * 16;
    conv_x_k<<<(nx8 + 255) / 256, 256, 0, stream>>>(x, ha, nx8);
    wprep0_k<<<256, 256, 0, stream>>>(lin_w, eps, w0b);
    conv_k<<<32, 256, 0, stream>>>(w1, w1b, 8192);
    conv_k<<<32, 256, 0, stream>>>(w2, w2b, 8192);
    conv_k<<<16, 256, 0, stream>>>(w3, w3b, 4096);

    // CSR build + gather
    detect_k<<<1, 256, 0, stream>>>((const int*)ei, flag);
    hist_k<<<(E + 255) / 256, 256, 0, stream>>>(ei, flag, E, counts);
    scan_k<<<1, 1024, 0, stream>>>(counts, offs, cursor, N, E);
    fill_k<<<(E + 255) / 256, 256, 0, stream>>>(ei, flag, E, cursor, csr);
    gather_k<<<(N + 3) / 4, 256, 0, stream>>>(ha, offs, csr, N);

    const int nb = (N + 127) / 128;
    // h = [x|agg] @ W2^T + lin_b   (linmaps + eps + transfer folded into W2)
    gemm_k<16, false, false, false, true><<<nb, 256, 0, stream>>>(
        ha, w0b, nullptr, nullptr, nullptr, nullptr, lin_b, hb, nullptr, N);
    // t1 = h@w1^T (+ BN1 stats)
    gemm_k<16, false, true, false, false><<<nb, 256, 0, stream>>>(
        hb, w1b, nullptr, nullptr, stats + 0, stats + 256, nullptr, ha, nullptr, N);
    finalize_k<<<1, 256, 0, stream>>>(stats + 0, stats + 256, g1, b1, scsh + 0, scsh + 256, 1.f / (float)N);
    // t2 = relu(BN1(t1))@w2^T (+ BN2 stats)
    gemm_k<16, true, true, false, false><<<nb, 256, 0, stream>>>(
        ha, w2b, scsh + 0, scsh + 256, stats + 512, stats + 768, nullptr, hb, nullptr, N);
    finalize_k<<<1, 256, 0, stream>>>(stats + 512, stats + 768, g2, b2, scsh + 512, scsh + 768, 1.f / (float)N);
    // out = relu(BN2(t2))@w3^T + b3
    gemm_k<8, true, false, true, false><<<nb, 256, 0, stream>>>(
        hb, w3b, scsh + 512, scsh + 768, nullptr, nullptr, b3, nullptr, out, N);
}

// Round 3
// 595.380 us; speedup vs baseline: 2.2833x; 1.7081x over previous
//
#include <hip/hip_runtime.h>
#include <cstdint>
#include <cstddef>

typedef __bf16 bf16_t;
typedef __bf16 bf16x8 __attribute__((ext_vector_type(8)));
typedef __bf16 bf16x4 __attribute__((ext_vector_type(4)));
typedef float f32x4 __attribute__((ext_vector_type(4)));

__device__ __forceinline__ float bf2f(unsigned short u) {
    union { unsigned int i; float f; } c; c.i = ((unsigned int)u) << 16; return c.f;
}

// ---------------- conversions ----------------
__global__ void conv_k(const float* __restrict__ in, bf16_t* __restrict__ out, int n8) {
    int id = blockIdx.x * 256 + threadIdx.x;
    if (id >= n8) return;
    const float4* p = (const float4*)in;
    float4 a = p[2 * id], b = p[2 * id + 1];
    bf16x8 o;
    o[0] = (bf16_t)a.x; o[1] = (bf16_t)a.y; o[2] = (bf16_t)a.z; o[3] = (bf16_t)a.w;
    o[4] = (bf16_t)b.x; o[5] = (bf16_t)b.y; o[6] = (bf16_t)b.z; o[7] = (bf16_t)b.w;
    *(bf16x8*)(out + (size_t)id * 8) = o;
}

// x fp32 -> cols 0..127 of interleaved ha[N][256]
__global__ void conv_x_k(const float* __restrict__ in, bf16_t* __restrict__ ha, int n8) {
    int id = blockIdx.x * 256 + threadIdx.x;
    if (id >= n8) return;
    const float4* p = (const float4*)in;
    float4 a = p[2 * id], b = p[2 * id + 1];
    bf16x8 o;
    o[0] = (bf16_t)a.x; o[1] = (bf16_t)a.y; o[2] = (bf16_t)a.z; o[3] = (bf16_t)a.w;
    o[4] = (bf16_t)b.x; o[5] = (bf16_t)b.y; o[6] = (bf16_t)b.z; o[7] = (bf16_t)b.w;
    int row = id >> 4, ch = id & 15;
    *(bf16x8*)(ha + (size_t)row * 256 + ch * 8) = o;
}

// ---------------- merged weight: Wc = w1 @ W0, bcomb = w1 @ lin_b ----------------
// W0[j][k] = (k<128 ? lin_w[j][k] : 0) + delta((k&127)==(j&127)) * (k<128 ? 1+eps : 1)
// => Wc[c][k<128]  = dot(w1[c,:], lin_w[:,k]) + (1+eps)*(w1[c][k] + w1[c][k+128])
//    Wc[c][k>=128] = w1[c][k-128] + w1[c][k]
__global__ void wcomb_k(const float* __restrict__ w1, const float* __restrict__ lin_w,
                        const float* __restrict__ lin_b, const float* __restrict__ eps_p,
                        bf16_t* __restrict__ wc, float* __restrict__ bcomb) {
    __shared__ float red[256];
    int c = blockIdx.x, t = threadIdx.x;
    const float* w1row = w1 + c * 256;
    float onepe = 1.f + *eps_p;
    float v;
    if (t < 128) {
        float acc = 0.f;
        for (int j = 0; j < 256; j++) acc += w1row[j] * lin_w[j * 128 + t];
        v = acc + onepe * (w1row[t] + w1row[t + 128]);
    } else {
        int m = t - 128;
        v = w1row[m] + w1row[t];
    }
    wc[c * 256 + t] = (bf16_t)v;
    red[t] = w1row[t] * lin_b[t];
    __syncthreads();
    for (int off = 128; off > 0; off >>= 1) {
        if (t < off) red[t] += red[t + off];
        __syncthreads();
    }
    if (t == 0) bcomb[c] = red[0];
}

// ---------------- edge-index dtype detection ----------------
__global__ void detect_k(const int* __restrict__ ei, int* __restrict__ flag) {
    int v = ei[2 * threadIdx.x + 1];
    if (v != 0) atomicOr(flag, 1);   // 1 => int32 layout
}

__global__ void hist_k(const void* __restrict__ ei, const int* __restrict__ flag,
                       int E, int* __restrict__ counts) {
    int e = blockIdx.x * 256 + threadIdx.x;
    if (e >= E) return;
    int dst = (*flag) ? ((const int*)ei)[e] : (int)((const long long*)ei)[e];
    atomicAdd(&counts[dst], 1);
}

// ---------------- parallel scan: 2048 counts per block ----------------
__global__ __launch_bounds__(256) void scan1_k(const int* __restrict__ counts,
                                               int* __restrict__ offs,
                                               int* __restrict__ bsums, int N) {
    __shared__ int lds[256];
    int t = threadIdx.x;
    int base = blockIdx.x * 2048 + t * 8;
    int v[8], s = 0;
#pragma unroll
    for (int i = 0; i < 8; i++) {
        v[i] = (base + i < N) ? counts[base + i] : 0;
        s += v[i];
    }
    lds[t] = s;
    __syncthreads();
    for (int off = 1; off < 256; off <<= 1) {
        int add = (t >= off) ? lds[t - off] : 0;
        __syncthreads();
        lds[t] += add;
        __syncthreads();
    }
    int run = lds[t] - s;  // block-local exclusive prefix
#pragma unroll
    for (int i = 0; i < 8; i++) {
        if (base + i < N) offs[base + i] = run;
        run += v[i];
    }
    if (t == 255) bsums[blockIdx.x] = lds[255];
}

__global__ __launch_bounds__(1024) void scan2_k(int* __restrict__ bsums, int nb) {
    __shared__ int lds[1024];
    int t = threadIdx.x;
    int v = (t < nb) ? bsums[t] : 0;
    lds[t] = v;
    __syncthreads();
    for (int off = 1; off < 1024; off <<= 1) {
        int add = (t >= off) ? lds[t - off] : 0;
        __syncthreads();
        lds[t] += add;
        __syncthreads();
    }
    if (t < nb) bsums[t] = lds[t] - v;  // exclusive
}

__global__ void scan3_k(int* __restrict__ offs, int* __restrict__ cursor,
                        const int* __restrict__ bsums, int N, int E) {
    int i = blockIdx.x * 256 + threadIdx.x;
    if (i == 0) offs[N] = E;
    if (i >= N) return;
    int o = offs[i] + bsums[i >> 11];
    offs[i] = o;
    cursor[i] = o;
}

__global__ void fill_k(const void* __restrict__ ei, const int* __restrict__ flag,
                       int E, int* __restrict__ cursor, int* __restrict__ csr) {
    int e = blockIdx.x * 256 + threadIdx.x;
    if (e >= E) return;
    int dst, src;
    if (*flag) { dst = ((const int*)ei)[e]; src = ((const int*)ei)[E + e]; }
    else       { dst = (int)((const long long*)ei)[e]; src = (int)((const long long*)ei)[E + e]; }
    int pos = atomicAdd(&cursor[dst], 1);
    csr[pos] = src;
}

// one wave per node; 2 neighbors/iter (32 lanes x 8B each), 4-unrolled;
// reads bf16 x rows (cols 0..127 of ha), writes bf16 agg (cols 128..255)
__global__ void gather_k(bf16_t* __restrict__ ha, const int* __restrict__ offs,
                         const int* __restrict__ csr, int N) {
    int w = (blockIdx.x * 256 + threadIdx.x) >> 6;
    if (w >= N) return;
    int lane = threadIdx.x & 63;
    int g = lane >> 5, l5 = lane & 31;
    int s = offs[w], e = offs[w + 1];
    float a0 = 0.f, a1 = 0.f, a2 = 0.f, a3 = 0.f;
    int i = s;
    for (; i + 4 <= e; i += 4) {
        int s0 = csr[i + g], s1 = csr[i + 2 + g];
        uint2 v0 = *(const uint2*)(ha + (size_t)s0 * 256 + l5 * 4);
        uint2 v1 = *(const uint2*)(ha + (size_t)s1 * 256 + l5 * 4);
        a0 += bf2f((unsigned short)(v0.x & 0xffff)) + bf2f((unsigned short)(v1.x & 0xffff));
        a1 += bf2f((unsigned short)(v0.x >> 16))    + bf2f((unsigned short)(v1.x >> 16));
        a2 += bf2f((unsigned short)(v0.y & 0xffff)) + bf2f((unsigned short)(v1.y & 0xffff));
        a3 += bf2f((unsigned short)(v0.y >> 16))    + bf2f((unsigned short)(v1.y >> 16));
    }
    for (; i < e; i += 2) {
        int idx = i + g;
        if (idx < e) {
            int s0 = csr[idx];
            uint2 v0 = *(const uint2*)(ha + (size_t)s0 * 256 + l5 * 4);
            a0 += bf2f((unsigned short)(v0.x & 0xffff));
            a1 += bf2f((unsigned short)(v0.x >> 16));
            a2 += bf2f((unsigned short)(v0.y & 0xffff));
            a3 += bf2f((unsigned short)(v0.y >> 16));
        }
    }
    a0 += __shfl_xor(a0, 32);
    a1 += __shfl_xor(a1, 32);
    a2 += __shfl_xor(a2, 32);
    a3 += __shfl_xor(a3, 32);
    if (lane < 32) {
        bf16x4 o; o[0] = (bf16_t)a0; o[1] = (bf16_t)a1; o[2] = (bf16_t)a2; o[3] = (bf16_t)a3;
        *(bf16x4*)(ha + (size_t)w * 256 + 128 + l5 * 4) = o;
    }
}

// ---------------- K=256 MFMA GEMM, 128 rows/block, 32 rows/wave ----------------
// mfma_f32_16x16x32_bf16 (m89-verified): A lane holds A[l&15][(l>>4)*8+i];
// B lane holds B[k][l&15]; D reg i <-> out[row=(l>>4)*4+i][col=l&15].
template<int OT, bool BNIN, bool STATS, bool FINAL, bool BIAS>
__global__ __launch_bounds__(256) void gemm_k(
    const bf16_t* __restrict__ A, const bf16_t* __restrict__ W,
    const float* __restrict__ scale, const float* __restrict__ shift,
    float* __restrict__ sums, float* __restrict__ sqs,
    const float* __restrict__ bias,
    bf16_t* __restrict__ Obf, float* __restrict__ Of, int N)
{
    __shared__ float ls[BNIN ? 256 : 1], lh[BNIN ? 256 : 1];
    __shared__ float ps[STATS ? 4 : 1][STATS ? 256 : 1];
    __shared__ float pq[STATS ? 4 : 1][STATS ? 256 : 1];
    if constexpr (BNIN) {
        int t = threadIdx.x;
        ls[t] = scale[t]; lh[t] = shift[t];
        __syncthreads();
    }
    const int lane = threadIdx.x & 63, wid = threadIdx.x >> 6;
    const int l15 = lane & 15, l4 = lane >> 4;
    const int rows0 = blockIdx.x * 128 + wid * 32;
    int ra0 = rows0 + l15;      if (ra0 > N - 1) ra0 = N - 1;
    int ra1 = rows0 + 16 + l15; if (ra1 > N - 1) ra1 = N - 1;
    f32x4 acc0[OT], acc1[OT];
#pragma unroll
    for (int i = 0; i < OT; i++) { acc0[i] = f32x4{0.f,0.f,0.f,0.f}; acc1[i] = f32x4{0.f,0.f,0.f,0.f}; }
    const int kb = l4 * 8;
#pragma unroll
    for (int ks = 0; ks < 8; ks++) {
        int k0 = ks * 32 + kb;
        bf16x8 a0 = *(const bf16x8*)(A + (size_t)ra0 * 256 + k0);
        bf16x8 a1 = *(const bf16x8*)(A + (size_t)ra1 * 256 + k0);
        if constexpr (BNIN) {
            bf16x8 t0, t1;
#pragma unroll
            for (int i = 0; i < 8; i++) {
                float sc = ls[k0 + i], sh = lh[k0 + i];
                float f0 = (float)a0[i] * sc + sh; f0 = f0 > 0.f ? f0 : 0.f; t0[i] = (bf16_t)f0;
                float f1 = (float)a1[i] * sc + sh; f1 = f1 > 0.f ? f1 : 0.f; t1[i] = (bf16_t)f1;
            }
            a0 = t0; a1 = t1;
        }
#pragma unroll
        for (int ot = 0; ot < OT; ot++) {
            bf16x8 b = *(const bf16x8*)(W + (size_t)(ot * 16 + l15) * 256 + k0);
            acc0[ot] = __builtin_amdgcn_mfma_f32_16x16x32_bf16(a0, b, acc0[ot], 0, 0, 0);
            acc1[ot] = __builtin_amdgcn_mfma_f32_16x16x32_bf16(a1, b, acc1[ot], 0, 0, 0);
        }
    }
    const int rb0 = rows0 + l4 * 4, rb1 = rows0 + 16 + l4 * 4;
#pragma unroll
    for (int ot = 0; ot < OT; ot++) {
        int c = ot * 16 + l15;
        float s = 0.f, q = 0.f;
#pragma unroll
        for (int half = 0; half < 2; half++) {
            int rb = half ? rb1 : rb0;
            f32x4 av = half ? acc1[ot] : acc0[ot];
#pragma unroll
            for (int i = 0; i < 4; i++) {
                int r = rb + i;
                if constexpr (FINAL) {
                    if (r < N) Of[(size_t)r * (OT * 16) + c] = av[i] + bias[c];
                } else {
                    float v = av[i];
                    if constexpr (BIAS) v += bias[c];
                    bf16_t hv = (bf16_t)v;
                    if (r < N) Obf[(size_t)r * 256 + c] = hv;
                    if constexpr (STATS) {
                        float vv = (r < N) ? (float)hv : 0.f;
                        s += vv; q += vv * vv;
                    }
                }
            }
        }
        if constexpr (STATS) {
            s += __shfl_xor(s, 16); s += __shfl_xor(s, 32);
            q += __shfl_xor(q, 16); q += __shfl_xor(q, 32);
            if (lane < 16) { ps[wid][c] = s; pq[wid][c] = q; }
        }
    }
    if constexpr (STATS) {
        __syncthreads();
        int t = threadIdx.x;
        float S = ps[0][t] + ps[1][t] + ps[2][t] + ps[3][t];
        float Q = pq[0][t] + pq[1][t] + pq[2][t] + pq[3][t];
        atomicAdd(&sums[t], S);
        atomicAdd(&sqs[t], Q);
    }
}

__global__ void finalize_k(const float* __restrict__ sum, const float* __restrict__ sq,
                           const float* __restrict__ g, const float* __restrict__ b,
                           float* __restrict__ scale, float* __restrict__ shift, float invN) {
    int t = threadIdx.x;
    float mean = sum[t] * invN;
    float var = sq[t] * invN - mean * mean;
    float s = g[t] * rsqrtf(var + 1e-5f);
    scale[t] = s;
    shift[t] = b[t] - mean * s;
}

extern "C" void kernel_launch(void* const* d_in, const int* in_sizes, int n_in,
                              void* d_out, int out_size, void* d_ws, size_t ws_size,
                              hipStream_t stream)
{
    const int N = in_sizes[0] / 128;
    const int E = in_sizes[1] / 2;
    const float* x     = (const float*)d_in[0];
    const void*  ei    = d_in[1];
    const float* lin_w = (const float*)d_in[2];
    const float* lin_b = (const float*)d_in[3];
    const float* eps   = (const float*)d_in[4];
    const float* w1    = (const float*)d_in[5];
    const float* g1    = (const float*)d_in[6];
    const float* b1    = (const float*)d_in[7];
    const float* w2    = (const float*)d_in[8];
    const float* g2    = (const float*)d_in[9];
    const float* b2    = (const float*)d_in[10];
    const float* w3    = (const float*)d_in[11];
    const float* b3    = (const float*)d_in[12];
    float* out = (float*)d_out;

    char* ws = (char*)d_ws;
    size_t o = 0;
    auto alloc = [&](size_t bytes) -> char* {
        char* p = ws + o;
        o = (o + bytes + 255) & ~(size_t)255;
        return p;
    };
    bf16_t* ha     = (bf16_t*)alloc((size_t)N * 256 * 2);  // [x | agg], later t2
    bf16_t* hb     = (bf16_t*)alloc((size_t)N * 256 * 2);  // t1
    bf16_t* wcb    = (bf16_t*)alloc((size_t)256 * 256 * 2);
    bf16_t* w2b    = (bf16_t*)alloc((size_t)256 * 256 * 2);
    bf16_t* w3b    = (bf16_t*)alloc((size_t)128 * 256 * 2);
    float*  bcomb  = (float*)alloc(256 * 4);
    float*  stats  = (float*)alloc(4 * 256 * 4);  // sum1, sq1, sum2, sq2
    float*  scsh   = (float*)alloc(4 * 256 * 4);  // scale1, shift1, scale2, shift2
    int*    counts = (int*)alloc((size_t)(N + 1) * 4);
    int*    offs   = (int*)alloc((size_t)(N + 1) * 4);
    int*    cursor = (int*)alloc((size_t)N * 4);
    int*    csr    = (int*)alloc((size_t)E * 4);
    int*    bsums  = (int*)alloc(1024 * 4);
    int*    flag   = (int*)alloc(4);

    hipMemsetAsync(counts, 0, (size_t)(N + 1) * 4, stream);
    hipMemsetAsync(stats, 0, 4 * 256 * 4, stream);
    hipMemsetAsync(flag, 0, 4, stream);

    // conversions / weight prep
    int nx8 = N * 16;
    conv_x_k<<<(nx8 + 255) / 256, 256, 0, stream>>>(x, ha, nx8);
    wcomb_k<<<256, 256, 0, stream>>>(w1, lin_w, lin_b, eps, wcb, bcomb);
    conv_k<<<32, 256, 0, stream>>>(w2, w2b, 8192);
    conv_k<<<16, 256, 0, stream>>>(w3, w3b, 4096);

    // CSR build + gather
    const int nb1 = (N + 2047) / 2048;
    detect_k<<<1, 256, 0, stream>>>((const int*)ei, flag);
    hist_k<<<(E + 255) / 256, 256, 0, stream>>>(ei, flag, E, counts);
    scan1_k<<<nb1, 256, 0, stream>>>(counts, offs, bsums, N);
    scan2_k<<<1, 1024, 0, stream>>>(bsums, nb1);
    scan3_k<<<(N + 255) / 256, 256, 0, stream>>>(offs, cursor, bsums, N, E);
    fill_k<<<(E + 255) / 256, 256, 0, stream>>>(ei, flag, E, cursor, csr);
    gather_k<<<(N + 3) / 4, 256, 0, stream>>>(ha, offs, csr, N);

    const int nb = (N + 127) / 128;
    // t1 = [x|agg] @ Wc^T + bcomb   (GEMM0 algebraically merged into GEMM1; + BN1 stats)
    gemm_k<16, false, true, false, true><<<nb, 256, 0, stream>>>(
        ha, wcb, nullptr, nullptr, stats + 0, stats + 256, bcomb, hb, nullptr, N);
    finalize_k<<<1, 256, 0, stream>>>(stats + 0, stats + 256, g1, b1, scsh + 0, scsh + 256, 1.f / (float)N);
    // t2 = relu(BN1(t1))@w2^T (+ BN2 stats)
    gemm_k<16, true, true, false, false><<<nb, 256, 0, stream>>>(
        hb, w2b, scsh + 0, scsh + 256, stats + 512, stats + 768, nullptr, ha, nullptr, N);
    finalize_k<<<1, 256, 0, stream>>>(stats + 512, stats + 768, g2, b2, scsh + 512, scsh + 768, 1.f / (float)N);
    // out = relu(BN2(t2))@w3^T + b3
    gemm_k<8, true, false, true, false><<<nb, 256, 0, stream>>>(
        ha, w3b, scsh + 512, scsh + 768, nullptr, nullptr, b3, nullptr, out, N);
}

// Round 4
// 425.638 us; speedup vs baseline: 3.1939x; 1.3988x over previous
//
#include <hip/hip_runtime.h>
#include <cstdint>
#include <cstddef>

typedef __bf16 bf16_t;
typedef __bf16 bf16x8 __attribute__((ext_vector_type(8)));
typedef float f32x4 __attribute__((ext_vector_type(4)));

__device__ __forceinline__ float bf2f(unsigned short u) {
    union { unsigned int i; float f; } c; c.i = ((unsigned int)u) << 16; return c.f;
}

#define GLOBAL_AS __attribute__((address_space(1)))
#define LDS_AS    __attribute__((address_space(3)))

__device__ __forceinline__ void glds16(const void* g, void* l) {
    __builtin_amdgcn_global_load_lds((const GLOBAL_AS void*)g, (LDS_AS void*)l, 16, 0, 0);
}

// ---------------- conversions ----------------
__global__ void conv_k(const float* __restrict__ in, bf16_t* __restrict__ out, int n8) {
    int id = blockIdx.x * 256 + threadIdx.x;
    if (id >= n8) return;
    const float4* p = (const float4*)in;
    float4 a = p[2 * id], b = p[2 * id + 1];
    bf16x8 o;
    o[0] = (bf16_t)a.x; o[1] = (bf16_t)a.y; o[2] = (bf16_t)a.z; o[3] = (bf16_t)a.w;
    o[4] = (bf16_t)b.x; o[5] = (bf16_t)b.y; o[6] = (bf16_t)b.z; o[7] = (bf16_t)b.w;
    *(bf16x8*)(out + (size_t)id * 8) = o;
}

// x fp32 -> cols 0..127 of interleaved ha[N][256]
__global__ void conv_x_k(const float* __restrict__ in, bf16_t* __restrict__ ha, int n8) {
    int id = blockIdx.x * 256 + threadIdx.x;
    if (id >= n8) return;
    const float4* p = (const float4*)in;
    float4 a = p[2 * id], b = p[2 * id + 1];
    bf16x8 o;
    o[0] = (bf16_t)a.x; o[1] = (bf16_t)a.y; o[2] = (bf16_t)a.z; o[3] = (bf16_t)a.w;
    o[4] = (bf16_t)b.x; o[5] = (bf16_t)b.y; o[6] = (bf16_t)b.z; o[7] = (bf16_t)b.w;
    int row = id >> 4, ch = id & 15;
    *(bf16x8*)(ha + (size_t)row * 256 + ch * 8) = o;
}

// ---------------- merged weight: Wc = w1 @ W0, bcomb = w1 @ lin_b ----------------
__global__ void wcomb_k(const float* __restrict__ w1, const float* __restrict__ lin_w,
                        const float* __restrict__ lin_b, const float* __restrict__ eps_p,
                        bf16_t* __restrict__ wc, float* __restrict__ bcomb) {
    __shared__ float red[256];
    int c = blockIdx.x, t = threadIdx.x;
    const float* w1row = w1 + c * 256;
    float onepe = 1.f + *eps_p;
    float v;
    if (t < 128) {
        float acc = 0.f;
        for (int j = 0; j < 256; j++) acc += w1row[j] * lin_w[j * 128 + t];
        v = acc + onepe * (w1row[t] + w1row[t + 128]);
    } else {
        int m = t - 128;
        v = w1row[m] + w1row[t];
    }
    wc[c * 256 + t] = (bf16_t)v;
    red[t] = w1row[t] * lin_b[t];
    __syncthreads();
    for (int off = 128; off > 0; off >>= 1) {
        if (t < off) red[t] += red[t + off];
        __syncthreads();
    }
    if (t == 0) bcomb[c] = red[0];
}

// ---------------- edge-index dtype detection ----------------
__global__ void detect_k(const int* __restrict__ ei, int* __restrict__ flag) {
    int v = ei[2 * threadIdx.x + 1];
    if (v != 0) atomicOr(flag, 1);   // 1 => int32 layout
}

__global__ void hist_k(const void* __restrict__ ei, const int* __restrict__ flag,
                       int E, int* __restrict__ counts) {
    int e = blockIdx.x * 256 + threadIdx.x;
    if (e >= E) return;
    int dst = (*flag) ? ((const int*)ei)[e] : (int)((const long long*)ei)[e];
    atomicAdd(&counts[dst], 1);
}

// ---------------- parallel scan: 2048 counts per block ----------------
__global__ __launch_bounds__(256) void scan1_k(const int* __restrict__ counts,
                                               int* __restrict__ offs,
                                               int* __restrict__ bsums, int N) {
    __shared__ int lds[256];
    int t = threadIdx.x;
    int base = blockIdx.x * 2048 + t * 8;
    int v[8], s = 0;
#pragma unroll
    for (int i = 0; i < 8; i++) {
        v[i] = (base + i < N) ? counts[base + i] : 0;
        s += v[i];
    }
    lds[t] = s;
    __syncthreads();
    for (int off = 1; off < 256; off <<= 1) {
        int add = (t >= off) ? lds[t - off] : 0;
        __syncthreads();
        lds[t] += add;
        __syncthreads();
    }
    int run = lds[t] - s;
#pragma unroll
    for (int i = 0; i < 8; i++) {
        if (base + i < N) offs[base + i] = run;
        run += v[i];
    }
    if (t == 255) bsums[blockIdx.x] = lds[255];
}

__global__ __launch_bounds__(1024) void scan2_k(int* __restrict__ bsums, int nb) {
    __shared__ int lds[1024];
    int t = threadIdx.x;
    int v = (t < nb) ? bsums[t] : 0;
    lds[t] = v;
    __syncthreads();
    for (int off = 1; off < 1024; off <<= 1) {
        int add = (t >= off) ? lds[t - off] : 0;
        __syncthreads();
        lds[t] += add;
        __syncthreads();
    }
    if (t < nb) bsums[t] = lds[t] - v;  // exclusive
}

__global__ void scan3_k(int* __restrict__ offs, int* __restrict__ cursor,
                        const int* __restrict__ bsums, int N, int E) {
    int i = blockIdx.x * 256 + threadIdx.x;
    if (i == 0) offs[N] = E;
    if (i >= N) return;
    int o = offs[i] + bsums[i >> 11];
    offs[i] = o;
    cursor[i] = o;
}

__global__ void fill_k(const void* __restrict__ ei, const int* __restrict__ flag,
                       int E, int* __restrict__ cursor, int* __restrict__ csr) {
    int e = blockIdx.x * 256 + threadIdx.x;
    if (e >= E) return;
    int dst, src;
    if (*flag) { dst = ((const int*)ei)[e]; src = ((const int*)ei)[E + e]; }
    else       { dst = (int)((const long long*)ei)[e]; src = (int)((const long long*)ei)[E + e]; }
    int pos = atomicAdd(&cursor[dst], 1);
    csr[pos] = src;
}

// one wave per node; 4 neighbor rows in flight, 16 lanes x 16B (bf16x8) per row
__global__ __launch_bounds__(256) void gather_k(bf16_t* __restrict__ ha, const int* __restrict__ offs,
                                                const int* __restrict__ csr, int N) {
    int w = (blockIdx.x * 256 + threadIdx.x) >> 6;
    if (w >= N) return;
    int lane = threadIdx.x & 63;
    int g = lane >> 4, l15 = lane & 15;
    int s = offs[w], e = offs[w + 1];
    float acc[8] = {0.f, 0.f, 0.f, 0.f, 0.f, 0.f, 0.f, 0.f};
    for (int i = s + g; i < e; i += 4) {
        int src = csr[i];
        bf16x8 v = *(const bf16x8*)(ha + (size_t)src * 256 + l15 * 8);
#pragma unroll
        for (int j = 0; j < 8; j++) acc[j] += (float)v[j];
    }
#pragma unroll
    for (int j = 0; j < 8; j++) {
        acc[j] += __shfl_xor(acc[j], 16);
        acc[j] += __shfl_xor(acc[j], 32);
    }
    if (g == 0) {
        bf16x8 o;
#pragma unroll
        for (int j = 0; j < 8; j++) o[j] = (bf16_t)acc[j];
        *(bf16x8*)(ha + (size_t)w * 256 + 128 + l15 * 8) = o;
    }
}

// ---------------- LDS-staged K=256 MFMA GEMM ----------------
// W [NCOL][256] staged in LDS chunks [NCOL][BK=32] (layout [col][32], provably
// conflict-free for the B-frag ds_read_b128), double-buffered via
// global_load_lds; A direct-from-global with one-chunk register prefetch.
// Block: NCOL*2 threads; waves = 4 row-groups x (NCOL/128) col-groups; BM=128.
// mfma_f32_16x16x32_bf16 (m89): A lane A[l&15][(l>>4)*8+i]; B lane B[k][l&15];
// D reg i <-> out[row=(l>>4)*4+i][col=l&15].
template<int NCOL, bool BNIN, bool STATS, bool FINAL, bool BIAS>
__global__ __launch_bounds__(NCOL * 2, 4) void gemm_k(
    const bf16_t* __restrict__ A, const bf16_t* __restrict__ W,
    const float2* __restrict__ scsh2,
    float* __restrict__ sums, float* __restrict__ sqs,
    const float* __restrict__ bias,
    bf16_t* __restrict__ Obf, float* __restrict__ Of, int N)
{
    constexpr int NW = NCOL / 32;   // waves per block: 8 (NCOL=256) or 4 (NCOL=128)
    __shared__ __align__(16) bf16_t wl[2][NCOL * 32];
    __shared__ float2 ssl[BNIN ? 256 : 1];
    __shared__ float ps[STATS ? NW : 1][STATS ? 128 : 1];
    __shared__ float pq[STATS ? NW : 1][STATS ? 128 : 1];

    const int tid = threadIdx.x;
    if constexpr (BNIN) { if (tid < 256) ssl[tid] = scsh2[tid]; }
    const int lane = tid & 63, wid = tid >> 6;
    const int l15 = lane & 15, l4 = lane >> 4;
    const int wr = wid & 3, wc = wid >> 2;
    const int rows0 = blockIdx.x * 128 + wr * 32;
    int ra0 = rows0 + l15;      if (ra0 > N - 1) ra0 = N - 1;
    int ra1 = rows0 + 16 + l15; if (ra1 > N - 1) ra1 = N - 1;

    auto stage = [&](int buf, int c) {
#pragma unroll
        for (int s = 0; s < 2; s++) {
            int d = ((s * NW + wid) * 64 + lane) * 16;   // byte offset, wave-linear dest
            int col = d >> 6, koff = d & 63;
            glds16((const char*)W + (size_t)col * 512 + c * 64 + koff,
                   (char*)&wl[buf][0] + d);
        }
    };
    stage(0, 0);
    __syncthreads();

    f32x4 acc0[8], acc1[8];
#pragma unroll
    for (int i = 0; i < 8; i++) { acc0[i] = f32x4{0.f,0.f,0.f,0.f}; acc1[i] = f32x4{0.f,0.f,0.f,0.f}; }

    bf16x8 pa0 = *(const bf16x8*)(A + (size_t)ra0 * 256 + l4 * 8);
    bf16x8 pa1 = *(const bf16x8*)(A + (size_t)ra1 * 256 + l4 * 8);

    for (int c = 0; c < 8; c++) {
        const int buf = c & 1;
        if (c + 1 < 8) stage(buf ^ 1, c + 1);
        bf16x8 ca0 = pa0, ca1 = pa1;
        if (c + 1 < 8) {
            int kn = (c + 1) * 32 + l4 * 8;
            pa0 = *(const bf16x8*)(A + (size_t)ra0 * 256 + kn);
            pa1 = *(const bf16x8*)(A + (size_t)ra1 * 256 + kn);
        }
        if constexpr (BNIN) {
            const int k0 = c * 32 + l4 * 8;
            bf16x8 t0, t1;
#pragma unroll
            for (int i = 0; i < 8; i++) {
                float2 ss = ssl[k0 + i];
                float f0 = (float)ca0[i] * ss.x + ss.y; f0 = fmaxf(f0, 0.f);
                float f1 = (float)ca1[i] * ss.x + ss.y; f1 = fmaxf(f1, 0.f);
                t0[i] = (bf16_t)f0; t1[i] = (bf16_t)f1;
            }
            ca0 = t0; ca1 = t1;
        }
#pragma unroll
        for (int ot = 0; ot < 8; ot++) {
            int colw = wc * 128 + ot * 16 + l15;
            const bf16x8 b = *(const bf16x8*)((const char*)&wl[buf][0] + colw * 64 + l4 * 16);
            acc0[ot] = __builtin_amdgcn_mfma_f32_16x16x32_bf16(ca0, b, acc0[ot], 0, 0, 0);
            acc1[ot] = __builtin_amdgcn_mfma_f32_16x16x32_bf16(ca1, b, acc1[ot], 0, 0, 0);
        }
        __syncthreads();
    }

    const int rb0 = rows0 + l4 * 4, rb1 = rows0 + 16 + l4 * 4;
#pragma unroll
    for (int ot = 0; ot < 8; ot++) {
        int colw = wc * 128 + ot * 16 + l15;
        float s = 0.f, q = 0.f;
#pragma unroll
        for (int half = 0; half < 2; half++) {
            int rb = half ? rb1 : rb0;
            f32x4 av = half ? acc1[ot] : acc0[ot];
#pragma unroll
            for (int i = 0; i < 4; i++) {
                int r = rb + i;
                if constexpr (FINAL) {
                    if (r < N) Of[(size_t)r * NCOL + colw] = av[i] + bias[colw];
                } else {
                    float v = av[i];
                    if constexpr (BIAS) v += bias[colw];
                    bf16_t hv = (bf16_t)v;
                    if (r < N) Obf[(size_t)r * 256 + colw] = hv;
                    if constexpr (STATS) {
                        float vv = (r < N) ? (float)hv : 0.f;
                        s += vv; q += vv * vv;
                    }
                }
            }
        }
        if constexpr (STATS) {
            s += __shfl_xor(s, 16); s += __shfl_xor(s, 32);
            q += __shfl_xor(q, 16); q += __shfl_xor(q, 32);
            if (lane < 16) { ps[wid][ot * 16 + l15] = s; pq[wid][ot * 16 + l15] = q; }
        }
    }
    if constexpr (STATS) {
        __syncthreads();
        if (tid < 256) {
            int gq = (tid >> 7) * 4, cl = tid & 127;
            atomicAdd(&sums[tid], ps[gq][cl] + ps[gq + 1][cl] + ps[gq + 2][cl] + ps[gq + 3][cl]);
        } else {
            int u = tid - 256;
            int gq = (u >> 7) * 4, cl = u & 127;
            atomicAdd(&sqs[u], pq[gq][cl] + pq[gq + 1][cl] + pq[gq + 2][cl] + pq[gq + 3][cl]);
        }
    }
}

__global__ void finalize_k(const float* __restrict__ sum, const float* __restrict__ sq,
                           const float* __restrict__ g, const float* __restrict__ b,
                           float2* __restrict__ scsh2, float invN) {
    int t = threadIdx.x;
    float mean = sum[t] * invN;
    float var = sq[t] * invN - mean * mean;
    float s = g[t] * rsqrtf(var + 1e-5f);
    scsh2[t] = make_float2(s, b[t] - mean * s);
}

extern "C" void kernel_launch(void* const* d_in, const int* in_sizes, int n_in,
                              void* d_out, int out_size, void* d_ws, size_t ws_size,
                              hipStream_t stream)
{
    const int N = in_sizes[0] / 128;
    const int E = in_sizes[1] / 2;
    const float* x     = (const float*)d_in[0];
    const void*  ei    = d_in[1];
    const float* lin_w = (const float*)d_in[2];
    const float* lin_b = (const float*)d_in[3];
    const float* eps   = (const float*)d_in[4];
    const float* w1    = (const float*)d_in[5];
    const float* g1    = (const float*)d_in[6];
    const float* b1    = (const float*)d_in[7];
    const float* w2    = (const float*)d_in[8];
    const float* g2    = (const float*)d_in[9];
    const float* b2    = (const float*)d_in[10];
    const float* w3    = (const float*)d_in[11];
    const float* b3    = (const float*)d_in[12];
    float* out = (float*)d_out;

    char* ws = (char*)d_ws;
    size_t o = 0;
    auto alloc = [&](size_t bytes) -> char* {
        char* p = ws + o;
        o = (o + bytes + 255) & ~(size_t)255;
        return p;
    };
    bf16_t* ha     = (bf16_t*)alloc((size_t)N * 256 * 2);  // [x | agg], later t2
    bf16_t* hb     = (bf16_t*)alloc((size_t)N * 256 * 2);  // t1
    bf16_t* wcb    = (bf16_t*)alloc((size_t)256 * 256 * 2);
    bf16_t* w2b    = (bf16_t*)alloc((size_t)256 * 256 * 2);
    bf16_t* w3b    = (bf16_t*)alloc((size_t)128 * 256 * 2);
    float*  bcomb  = (float*)alloc(256 * 4);
    float*  stats  = (float*)alloc(4 * 256 * 4);   // sum1, sq1, sum2, sq2
    float2* scsh1  = (float2*)alloc(256 * 8);
    float2* scsh2  = (float2*)alloc(256 * 8);
    int*    counts = (int*)alloc((size_t)(N + 1) * 4);
    int*    offs   = (int*)alloc((size_t)(N + 1) * 4);
    int*    cursor = (int*)alloc((size_t)N * 4);
    int*    csr    = (int*)alloc((size_t)E * 4);
    int*    bsums  = (int*)alloc(1024 * 4);
    int*    flag   = (int*)alloc(4);

    hipMemsetAsync(counts, 0, (size_t)(N + 1) * 4, stream);
    hipMemsetAsync(stats, 0, 4 * 256 * 4, stream);
    hipMemsetAsync(flag, 0, 4, stream);

    // conversions / weight prep
    int nx8 = N * 16;
    conv_x_k<<<(nx8 + 255) / 256, 256, 0, stream>>>(x, ha, nx8);
    wcomb_k<<<256, 256, 0, stream>>>(w1, lin_w, lin_b, eps, wcb, bcomb);
    conv_k<<<32, 256, 0, stream>>>(w2, w2b, 8192);
    conv_k<<<16, 256, 0, stream>>>(w3, w3b, 4096);

    // CSR build + gather
    const int nb1 = (N + 2047) / 2048;
    detect_k<<<1, 256, 0, stream>>>((const int*)ei, flag);
    hist_k<<<(E + 255) / 256, 256, 0, stream>>>(ei, flag, E, counts);
    scan1_k<<<nb1, 256, 0, stream>>>(counts, offs, bsums, N);
    scan2_k<<<1, 1024, 0, stream>>>(bsums, nb1);
    scan3_k<<<(N + 255) / 256, 256, 0, stream>>>(offs, cursor, bsums, N, E);
    fill_k<<<(E + 255) / 256, 256, 0, stream>>>(ei, flag, E, cursor, csr);
    gather_k<<<(N + 3) / 4, 256, 0, stream>>>(ha, offs, csr, N);

    const int nb = (N + 127) / 128;
    // t1 = [x|agg] @ Wc^T + bcomb (+ BN1 stats)
    gemm_k<256, false, true, false, true><<<nb, 512, 0, stream>>>(
        ha, wcb, nullptr, stats + 0, stats + 256, bcomb, hb, nullptr, N);
    finalize_k<<<1, 256, 0, stream>>>(stats + 0, stats + 256, g1, b1, scsh1, 1.f / (float)N);
    // t2 = relu(BN1(t1))@w2^T (+ BN2 stats)
    gemm_k<256, true, true, false, false><<<nb, 512, 0, stream>>>(
        hb, w2b, scsh1, stats + 512, stats + 768, nullptr, ha, nullptr, N);
    finalize_k<<<1, 256, 0, stream>>>(stats + 512, stats + 768, g2, b2, scsh2, 1.f / (float)N);
    // out = relu(BN2(t2))@w3^T + b3
    gemm_k<128, true, false, true, true><<<nb, 256, 0, stream>>>(
        ha, w3b, scsh2, nullptr, nullptr, b3, nullptr, out, N);
}